// Round 6
// baseline (277.979 us; speedup 1.0000x reference)
//
#include <hip/hip_runtime.h>

#define NN 100000
#define NE 1600000
#define DD 128

constexpr int NP = 100096;
constexpr int SCAN_BLKS = (NN + 255) / 256; // 391

typedef __attribute__((ext_vector_type(8))) short bf16x8;
typedef __attribute__((ext_vector_type(4))) float f32x4;

__device__ inline unsigned short f2bf(float f) {
  union { float f; unsigned u; } v; v.f = f;
  unsigned r = (v.u + 0x7FFF + ((v.u >> 16) & 1)) >> 16;
  return (unsigned short)r;
}

// ---- K1: packed degree+count atomic; returns per-edge CSR slot ----
__global__ __launch_bounds__(256) void k_deg(const int* __restrict__ col,
    const float* __restrict__ ew, unsigned long long* __restrict__ degcnt,
    int* __restrict__ epos, int E) {
  for (int e = blockIdx.x * blockDim.x + threadIdx.x; e < E; e += gridDim.x * blockDim.x) {
    int c = col[e];
    unsigned long long fx = (unsigned long long)(ew[e] * 1073741824.0f + 0.5f);
    unsigned long long old = atomicAdd(&degcnt[c], (1ULL << 48) | fx);
    epos[e] = (int)(old >> 48);
  }
}

// ---- K_cast: xb = bf16(x) ----
__global__ __launch_bounds__(256) void k_cast(const float* __restrict__ x,
    unsigned short* __restrict__ xb, int total8) {
  for (int i = blockIdx.x * blockDim.x + threadIdx.x; i < total8; i += gridDim.x * blockDim.x) {
    float4 a = *(const float4*)&x[i * 8];
    float4 b = *(const float4*)&x[i * 8 + 4];
    unsigned short o[8] = {f2bf(a.x), f2bf(a.y), f2bf(a.z), f2bf(a.w),
                           f2bf(b.x), f2bf(b.y), f2bf(b.z), f2bf(b.w)};
    *(uint4*)&xb[i * 8] = *(uint4*)o;
  }
}

// ---- K2a/b/c: hierarchical scan over packed counts ----
__global__ __launch_bounds__(256) void k_scan1(const unsigned long long* __restrict__ degcnt,
    int* __restrict__ bsum, int N) {
  int i = blockIdx.x * 256 + threadIdx.x;
  int v = (i < N) ? (int)(degcnt[i] >> 48) : 0;
  __shared__ int ws[4];
  #pragma unroll
  for (int off = 32; off >= 1; off >>= 1) v += __shfl_down(v, off, 64);
  if ((threadIdx.x & 63) == 0) ws[threadIdx.x >> 6] = v;
  __syncthreads();
  if (threadIdx.x == 0) bsum[blockIdx.x] = ws[0] + ws[1] + ws[2] + ws[3];
}

__global__ __launch_bounds__(512) void k_scan2(int* __restrict__ bsum, int B) {
  __shared__ int ps[512];
  int t = threadIdx.x;
  int v = (t < B) ? bsum[t] : 0;
  ps[t] = v;
  __syncthreads();
  for (int off = 1; off < 512; off <<= 1) {
    int u = (t >= off) ? ps[t - off] : 0;
    __syncthreads();
    ps[t] += u;
    __syncthreads();
  }
  if (t < B) bsum[t] = ps[t] - v;
}

__global__ __launch_bounds__(256) void k_scan3(const unsigned long long* __restrict__ degcnt,
    const int* __restrict__ boff, float* __restrict__ dis, int* __restrict__ rowptr, int N) {
  __shared__ int ps[256];
  int i = blockIdx.x * 256 + threadIdx.x;
  int t = threadIdx.x;
  unsigned long long v64 = (i < N) ? degcnt[i] : 0ULL;
  int v = (int)(v64 >> 48);
  ps[t] = v;
  __syncthreads();
  for (int off = 1; off < 256; off <<= 1) {
    int u = (t >= off) ? ps[t - off] : 0;
    __syncthreads();
    ps[t] += u;
    __syncthreads();
  }
  if (i < N) {
    int excl = boff[blockIdx.x] + ps[t] - v;
    rowptr[i] = excl;
    if (i == N - 1) rowptr[N] = excl + v;
    float d = (float)(v64 & 0xFFFFFFFFFFFFULL) * (1.0f / 1073741824.0f);
    dis[i] = (d > 0.0f) ? rsqrtf(d) : 0.0f;
  }
}

// ---- K3: fill CSR, atomic-free: edgeA[pos] = (wn_bits<<32) | src ----
__global__ __launch_bounds__(256) void k_fill(const int* __restrict__ row, const int* __restrict__ col,
    const float* __restrict__ ew, const float* __restrict__ dis, const int* __restrict__ rowptr,
    const int* __restrict__ epos, unsigned long long* __restrict__ edgeA, int E) {
  for (int e = blockIdx.x * blockDim.x + threadIdx.x; e < E; e += gridDim.x * blockDim.x) {
    int c = col[e], r = row[e];
    int pos = rowptr[c] + epos[e];
    float wn = dis[r] * ew[e] * dis[c];
    unsigned wb = __float_as_uint(wn);
    edgeA[pos] = ((unsigned long long)wb << 32) | (unsigned)r;
  }
}

// ---- K_wt2: WT2[j][k] = bf16 of [Wl;Wg]^T: k<128 -> Wl[k][j], else Wg[k-128][j] ----
__global__ __launch_bounds__(64) void k_wt2(const float* __restrict__ Wl,
    const float* __restrict__ Wg, unsigned short* __restrict__ WT2) {
  int j = blockIdx.x; // 0..127
  for (int k = threadIdx.x; k < 256; k += 64) {
    const float* W = (k < DD) ? Wl : Wg;
    WT2[j * 256 + k] = f2bf(W[(k & (DD - 1)) * DD + j]);
  }
}

// ---- K5: gather y = S @ xb (bf16 out, no RMW) ----
__global__ __launch_bounds__(256) void k_gather(const unsigned short* __restrict__ xb,
    const int* __restrict__ rowptr, const unsigned long long* __restrict__ edgeA,
    unsigned short* __restrict__ yb, int N) {
  int wid = (blockIdx.x * blockDim.x + threadIdx.x) >> 6;
  int lane = threadIdx.x & 63;
  if (wid >= N) return;
  int beg = rowptr[wid], end = rowptr[wid + 1];
  float ax = 0.f, ay = 0.f;
  for (int base = beg; base < end; base += 64) {
    int nv = min(64, end - base);
    int idx = base + lane;
    int s = 0, wb = 0;
    if (idx < end) {
      unsigned long long ev = edgeA[idx];
      s = (int)(unsigned)ev;
      wb = (int)(unsigned)(ev >> 32);
    }
    for (int i = 0; i < nv; i++) {
      int si = __shfl(s, i, 64);
      float wi = __uint_as_float((unsigned)__shfl(wb, i, 64));
      unsigned hv = *(const unsigned*)&xb[(size_t)si * DD + lane * 2];
      union { unsigned u; float f; } lo, hi;
      lo.u = hv << 16;
      hi.u = hv & 0xFFFF0000u;
      ax += wi * lo.f;
      ay += wi * hi.f;
    }
  }
  unsigned short o2[2] = {f2bf(ax), f2bf(ay)};
  *(unsigned*)&yb[(size_t)wid * DD + lane * 2] = *(unsigned*)o2;
}

// ---- K4: fused GEMM: out = [xb | yb] @ WT2^T  (M=N, K=256, Nout=128) ----
// block: 256 thr = 4 waves; BM=64; wave w owns output cols w*32..w*32+31
__global__ __launch_bounds__(256) void k_gemm(const unsigned short* __restrict__ xb,
    const unsigned short* __restrict__ yb, const unsigned short* __restrict__ WT2,
    float* __restrict__ out, int N) {
  __shared__ __align__(16) unsigned short Bl[128 * 256]; // 64KB, swizzled (row = 512B)
  __shared__ __align__(16) unsigned short Al[64 * 256];  // 32KB, swizzled
  int t = threadIdx.x;
  int rowbase = blockIdx.x * 64;

  // stage B: 128 rows x 256 bf16 = 4096 x 16B chunks
  const uint4* WTv = (const uint4*)WT2;
  #pragma unroll
  for (int i = 0; i < 16; i++) {
    int ci = t + i * 256;            // 0..4095
    int j = ci >> 5, c16 = ci & 31;  // 32 chunks per row
    uint4 v = WTv[ci];
    int byte = j * 512 + c16 * 16;
    byte ^= (j & 7) << 4;
    *(uint4*)((char*)Bl + byte) = v;
  }
  // stage A: 64 rows x 256 bf16; k<128 from xb, k>=128 from yb
  #pragma unroll
  for (int i = 0; i < 8; i++) {
    int ci = t + i * 256;            // 0..2047
    int r = ci >> 5, c16 = ci & 31;
    int gr = rowbase + r;
    uint4 v = make_uint4(0, 0, 0, 0);
    if (gr < N) {
      if (c16 < 16) v = *(const uint4*)&xb[(size_t)gr * DD + c16 * 8];
      else          v = *(const uint4*)&yb[(size_t)gr * DD + (c16 - 16) * 8];
    }
    int byte = r * 512 + c16 * 16;
    byte ^= (r & 7) << 4;
    *(uint4*)((char*)Al + byte) = v;
  }
  __syncthreads();

  int wid = t >> 6, lane = t & 63;
  int wn = wid * 32;
  int l15 = lane & 15, l4 = lane >> 4;
  f32x4 acc[4][2] = {};
  #pragma unroll
  for (int kk = 0; kk < 8; kk++) {
    bf16x8 af[4], bfr[2];
    #pragma unroll
    for (int m = 0; m < 4; m++) {
      int r = m * 16 + l15;
      int byte = r * 512 + kk * 64 + l4 * 16;
      byte ^= (r & 7) << 4;
      af[m] = *(const bf16x8*)((const char*)Al + byte);
    }
    #pragma unroll
    for (int n = 0; n < 2; n++) {
      int r = wn + n * 16 + l15;
      int byte = r * 512 + kk * 64 + l4 * 16;
      byte ^= (r & 7) << 4;
      bfr[n] = *(const bf16x8*)((const char*)Bl + byte);
    }
    #pragma unroll
    for (int m = 0; m < 4; m++)
      #pragma unroll
      for (int n = 0; n < 2; n++)
        acc[m][n] = __builtin_amdgcn_mfma_f32_16x16x32_bf16(af[m], bfr[n], acc[m][n], 0, 0, 0);
  }

  // store: D layout col=lane&15, row=(lane>>4)*4+j
  #pragma unroll
  for (int m = 0; m < 4; m++) {
    int gr0 = rowbase + m * 16 + l4 * 4;
    #pragma unroll
    for (int n = 0; n < 2; n++) {
      int gc = wn + n * 16 + l15;
      #pragma unroll
      for (int j = 0; j < 4; j++) {
        int gr = gr0 + j;
        if (gr < N) out[(size_t)gr * DD + gc] = acc[m][n][j];
      }
    }
  }
}

extern "C" void kernel_launch(void* const* d_in, const int* in_sizes, int n_in,
                              void* d_out, int out_size, void* d_ws, size_t ws_size,
                              hipStream_t stream) {
  const float* x  = (const float*)d_in[0];
  const int*   ei = (const int*)d_in[1];
  const float* ew = (const float*)d_in[2];
  const float* Wl = (const float*)d_in[3];
  const float* Wg = (const float*)d_in[4];
  float* out = (float*)d_out;
  const int N = NN, E = NE;
  const int* row = ei;      // src
  const int* col = ei + E;  // dst

  char* base = (char*)d_ws;
  unsigned long long* degcnt = (unsigned long long*)base;         // NP u64 (zeroed)
  float* dis    = (float*)(base + (size_t)NP * 8);                // NP f32
  int*   rowptr = (int*)  (base + (size_t)NP * 12);               // NP i32 (N+1 used)
  int*   bsum   = (int*)  (base + (size_t)NP * 16);               // 4KB
  unsigned long long* edgeA = (unsigned long long*)(base + (size_t)NP * 16 + 4096); // E u64
  unsigned short* xb = (unsigned short*)((char*)edgeA + (size_t)NE * 8);  // N*DD bf16
  unsigned short* yb = xb + (size_t)NN * DD;                      // N*DD bf16
  int* epos = (int*)yb;  // E i32, aliases yb (dead before k_gather writes yb)
  unsigned short* WT2 = yb + (size_t)NN * DD;                     // 128*256 bf16

  hipMemsetAsync(base, 0, (size_t)NP * 8, stream); // degcnt

  k_deg<<<2048, 256, 0, stream>>>(col, ew, degcnt, epos, E);
  k_cast<<<2048, 256, 0, stream>>>(x, xb, NN * DD / 8);
  k_wt2<<<128, 64, 0, stream>>>(Wl, Wg, WT2);
  k_scan1<<<SCAN_BLKS, 256, 0, stream>>>(degcnt, bsum, N);
  k_scan2<<<1, 512, 0, stream>>>(bsum, SCAN_BLKS);
  k_scan3<<<SCAN_BLKS, 256, 0, stream>>>(degcnt, bsum, dis, rowptr, N);
  k_fill<<<2048, 256, 0, stream>>>(row, col, ew, dis, rowptr, epos, edgeA, E);
  k_gather<<<(N * 64 + 255) / 256, 256, 0, stream>>>(xb, rowptr, edgeA, yb, N);
  k_gemm<<<(N + 63) / 64, 256, 0, stream>>>(xb, yb, WT2, out, N);
}

// Round 7
// 233.603 us; speedup vs baseline: 1.1900x; 1.1900x over previous
//
#include <hip/hip_runtime.h>

#define NN 100000
#define NE 1600000
#define DD 128

constexpr int NP = 100096;
constexpr int SCAN_BLKS = (NN + 255) / 256; // 391

typedef __attribute__((ext_vector_type(8))) short bf16x8;
typedef __attribute__((ext_vector_type(4))) float f32x4;

__device__ inline unsigned short f2bf(float f) {
  union { float f; unsigned u; } v; v.f = f;
  unsigned r = (v.u + 0x7FFF + ((v.u >> 16) & 1)) >> 16;
  return (unsigned short)r;
}

// ---- K1: packed degree+count atomic; returns per-edge CSR slot ----
__global__ __launch_bounds__(256) void k_deg(const int* __restrict__ col,
    const float* __restrict__ ew, unsigned long long* __restrict__ degcnt,
    int* __restrict__ epos, int E) {
  for (int e = blockIdx.x * blockDim.x + threadIdx.x; e < E; e += gridDim.x * blockDim.x) {
    int c = col[e];
    unsigned long long fx = (unsigned long long)(ew[e] * 1073741824.0f + 0.5f);
    unsigned long long old = atomicAdd(&degcnt[c], (1ULL << 48) | fx);
    epos[e] = (int)(old >> 48);
  }
}

// ---- K_cast: xb = bf16(x) ----
__global__ __launch_bounds__(256) void k_cast(const float* __restrict__ x,
    unsigned short* __restrict__ xb, int total8) {
  for (int i = blockIdx.x * blockDim.x + threadIdx.x; i < total8; i += gridDim.x * blockDim.x) {
    float4 a = *(const float4*)&x[i * 8];
    float4 b = *(const float4*)&x[i * 8 + 4];
    unsigned short o[8] = {f2bf(a.x), f2bf(a.y), f2bf(a.z), f2bf(a.w),
                           f2bf(b.x), f2bf(b.y), f2bf(b.z), f2bf(b.w)};
    *(uint4*)&xb[i * 8] = *(uint4*)o;
  }
}

// ---- K2a/b/c: hierarchical scan over packed counts ----
__global__ __launch_bounds__(256) void k_scan1(const unsigned long long* __restrict__ degcnt,
    int* __restrict__ bsum, int N) {
  int i = blockIdx.x * 256 + threadIdx.x;
  int v = (i < N) ? (int)(degcnt[i] >> 48) : 0;
  __shared__ int ws[4];
  #pragma unroll
  for (int off = 32; off >= 1; off >>= 1) v += __shfl_down(v, off, 64);
  if ((threadIdx.x & 63) == 0) ws[threadIdx.x >> 6] = v;
  __syncthreads();
  if (threadIdx.x == 0) bsum[blockIdx.x] = ws[0] + ws[1] + ws[2] + ws[3];
}

__global__ __launch_bounds__(512) void k_scan2(int* __restrict__ bsum, int B) {
  __shared__ int ps[512];
  int t = threadIdx.x;
  int v = (t < B) ? bsum[t] : 0;
  ps[t] = v;
  __syncthreads();
  for (int off = 1; off < 512; off <<= 1) {
    int u = (t >= off) ? ps[t - off] : 0;
    __syncthreads();
    ps[t] += u;
    __syncthreads();
  }
  if (t < B) bsum[t] = ps[t] - v;
}

__global__ __launch_bounds__(256) void k_scan3(const unsigned long long* __restrict__ degcnt,
    const int* __restrict__ boff, float* __restrict__ dis, int* __restrict__ rowptr, int N) {
  __shared__ int ps[256];
  int i = blockIdx.x * 256 + threadIdx.x;
  int t = threadIdx.x;
  unsigned long long v64 = (i < N) ? degcnt[i] : 0ULL;
  int v = (int)(v64 >> 48);
  ps[t] = v;
  __syncthreads();
  for (int off = 1; off < 256; off <<= 1) {
    int u = (t >= off) ? ps[t - off] : 0;
    __syncthreads();
    ps[t] += u;
    __syncthreads();
  }
  if (i < N) {
    int excl = boff[blockIdx.x] + ps[t] - v;
    rowptr[i] = excl;
    if (i == N - 1) rowptr[N] = excl + v;
    float d = (float)(v64 & 0xFFFFFFFFFFFFULL) * (1.0f / 1073741824.0f);
    dis[i] = (d > 0.0f) ? rsqrtf(d) : 0.0f;
  }
}

// ---- K3: fill CSR, atomic-free: edgeA[pos] = (wn_bits<<32) | src ----
__global__ __launch_bounds__(256) void k_fill(const int* __restrict__ row, const int* __restrict__ col,
    const float* __restrict__ ew, const float* __restrict__ dis, const int* __restrict__ rowptr,
    const int* __restrict__ epos, unsigned long long* __restrict__ edgeA, int E) {
  for (int e = blockIdx.x * blockDim.x + threadIdx.x; e < E; e += gridDim.x * blockDim.x) {
    int c = col[e], r = row[e];
    int pos = rowptr[c] + epos[e];
    float wn = dis[r] * ew[e] * dis[c];
    unsigned wb = __float_as_uint(wn);
    edgeA[pos] = ((unsigned long long)wb << 32) | (unsigned)r;
  }
}

// ---- K_wt2: WT2[j][k] = bf16 of [Wl;Wg]^T: k<128 -> Wl[k][j], else Wg[k-128][j] ----
__global__ __launch_bounds__(64) void k_wt2(const float* __restrict__ Wl,
    const float* __restrict__ Wg, unsigned short* __restrict__ WT2) {
  int j = blockIdx.x; // 0..127
  for (int k = threadIdx.x; k < 256; k += 64) {
    const float* W = (k < DD) ? Wl : Wg;
    WT2[j * 256 + k] = f2bf(W[(k & (DD - 1)) * DD + j]);
  }
}

// ---- K5: gather y = S @ xb, 4 edges/iter, 16B loads, 2x unroll ----
// lane = 16*grp + l16; grp g handles edges i+g; l16 covers dims [l16*8, l16*8+8)
__global__ __launch_bounds__(256) void k_gather(const unsigned short* __restrict__ xb,
    const int* __restrict__ rowptr, const unsigned long long* __restrict__ edgeA,
    unsigned short* __restrict__ yb, int N) {
  int wid = (blockIdx.x * blockDim.x + threadIdx.x) >> 6;
  int lane = threadIdx.x & 63;
  if (wid >= N) return;
  int grp = lane >> 4, l16 = lane & 15;
  int beg = rowptr[wid], end = rowptr[wid + 1];
  float acc[8] = {};
  for (int base = beg; base < end; base += 64) {
    int nv = min(64, end - base);
    int idx = base + lane;
    int s = 0, wb = 0;
    if (idx < end) {
      unsigned long long ev = edgeA[idx];
      s = (int)(unsigned)ev;
      wb = (int)(unsigned)(ev >> 32);
    }
    for (int i = 0; i < nv; i += 8) {
      int ja = i + grp, jb = i + 4 + grp;
      int sa = __shfl(s, ja, 64);
      float wa = __uint_as_float((unsigned)__shfl(wb, ja, 64));
      int sb = __shfl(s, jb, 64);
      float wwb = __uint_as_float((unsigned)__shfl(wb, jb, 64));
      if (ja >= nv) { wa = 0.f; sa = 0; }
      if (jb >= nv) { wwb = 0.f; sb = 0; }
      // two independent 16B loads in flight
      uint4 ha = *(const uint4*)&xb[(size_t)sa * DD + l16 * 8];
      uint4 hb4 = *(const uint4*)&xb[(size_t)sb * DD + l16 * 8];
      union { uint4 v; unsigned u[4]; } qa, qb;
      qa.v = ha; qb.v = hb4;
      #pragma unroll
      for (int k = 0; k < 4; k++) {
        union { unsigned u; float f; } lo, hi;
        lo.u = qa.u[k] << 16;
        hi.u = qa.u[k] & 0xFFFF0000u;
        acc[2 * k]     += wa * lo.f;
        acc[2 * k + 1] += wa * hi.f;
        lo.u = qb.u[k] << 16;
        hi.u = qb.u[k] & 0xFFFF0000u;
        acc[2 * k]     += wwb * lo.f;
        acc[2 * k + 1] += wwb * hi.f;
      }
    }
  }
  // reduce across the 4 lane-groups (same l16)
  #pragma unroll
  for (int k = 0; k < 8; k++) {
    acc[k] += __shfl_xor(acc[k], 16, 64);
    acc[k] += __shfl_xor(acc[k], 32, 64);
  }
  if (grp == 0) {
    unsigned short o[8] = {f2bf(acc[0]), f2bf(acc[1]), f2bf(acc[2]), f2bf(acc[3]),
                           f2bf(acc[4]), f2bf(acc[5]), f2bf(acc[6]), f2bf(acc[7])};
    *(uint4*)&yb[(size_t)wid * DD + l16 * 8] = *(uint4*)o;
  }
}

// ---- K4: fused GEMM: out = [xb | yb] @ WT2^T  (M=N, K=256, Nout=128) ----
__global__ __launch_bounds__(256) void k_gemm(const unsigned short* __restrict__ xb,
    const unsigned short* __restrict__ yb, const unsigned short* __restrict__ WT2,
    float* __restrict__ out, int N) {
  __shared__ __align__(16) unsigned short Bl[128 * 256]; // 64KB, swizzled (row = 512B)
  __shared__ __align__(16) unsigned short Al[64 * 256];  // 32KB, swizzled
  int t = threadIdx.x;
  int rowbase = blockIdx.x * 64;

  const uint4* WTv = (const uint4*)WT2;
  #pragma unroll
  for (int i = 0; i < 16; i++) {
    int ci = t + i * 256;            // 0..4095
    int j = ci >> 5, c16 = ci & 31;  // 32 chunks per row
    uint4 v = WTv[ci];
    int byte = j * 512 + c16 * 16;
    byte ^= (j & 7) << 4;
    *(uint4*)((char*)Bl + byte) = v;
  }
  #pragma unroll
  for (int i = 0; i < 8; i++) {
    int ci = t + i * 256;            // 0..2047
    int r = ci >> 5, c16 = ci & 31;
    int gr = rowbase + r;
    uint4 v = make_uint4(0, 0, 0, 0);
    if (gr < N) {
      if (c16 < 16) v = *(const uint4*)&xb[(size_t)gr * DD + c16 * 8];
      else          v = *(const uint4*)&yb[(size_t)gr * DD + (c16 - 16) * 8];
    }
    int byte = r * 512 + c16 * 16;
    byte ^= (r & 7) << 4;
    *(uint4*)((char*)Al + byte) = v;
  }
  __syncthreads();

  int wid = t >> 6, lane = t & 63;
  int wn = wid * 32;
  int l15 = lane & 15, l4 = lane >> 4;
  f32x4 acc[4][2] = {};
  #pragma unroll
  for (int kk = 0; kk < 8; kk++) {
    bf16x8 af[4], bfr[2];
    #pragma unroll
    for (int m = 0; m < 4; m++) {
      int r = m * 16 + l15;
      int byte = r * 512 + kk * 64 + l4 * 16;
      byte ^= (r & 7) << 4;
      af[m] = *(const bf16x8*)((const char*)Al + byte);
    }
    #pragma unroll
    for (int n = 0; n < 2; n++) {
      int r = wn + n * 16 + l15;
      int byte = r * 512 + kk * 64 + l4 * 16;
      byte ^= (r & 7) << 4;
      bfr[n] = *(const bf16x8*)((const char*)Bl + byte);
    }
    #pragma unroll
    for (int m = 0; m < 4; m++)
      #pragma unroll
      for (int n = 0; n < 2; n++)
        acc[m][n] = __builtin_amdgcn_mfma_f32_16x16x32_bf16(af[m], bfr[n], acc[m][n], 0, 0, 0);
  }

  #pragma unroll
  for (int m = 0; m < 4; m++) {
    int gr0 = rowbase + m * 16 + l4 * 4;
    #pragma unroll
    for (int n = 0; n < 2; n++) {
      int gc = wn + n * 16 + l15;
      #pragma unroll
      for (int j = 0; j < 4; j++) {
        int gr = gr0 + j;
        if (gr < N) out[(size_t)gr * DD + gc] = acc[m][n][j];
      }
    }
  }
}

extern "C" void kernel_launch(void* const* d_in, const int* in_sizes, int n_in,
                              void* d_out, int out_size, void* d_ws, size_t ws_size,
                              hipStream_t stream) {
  const float* x  = (const float*)d_in[0];
  const int*   ei = (const int*)d_in[1];
  const float* ew = (const float*)d_in[2];
  const float* Wl = (const float*)d_in[3];
  const float* Wg = (const float*)d_in[4];
  float* out = (float*)d_out;
  const int N = NN, E = NE;
  const int* row = ei;      // src
  const int* col = ei + E;  // dst

  char* base = (char*)d_ws;
  unsigned long long* degcnt = (unsigned long long*)base;         // NP u64 (zeroed)
  float* dis    = (float*)(base + (size_t)NP * 8);                // NP f32
  int*   rowptr = (int*)  (base + (size_t)NP * 12);               // NP i32 (N+1 used)
  int*   bsum   = (int*)  (base + (size_t)NP * 16);               // 4KB
  unsigned long long* edgeA = (unsigned long long*)(base + (size_t)NP * 16 + 4096); // E u64
  unsigned short* xb = (unsigned short*)((char*)edgeA + (size_t)NE * 8);  // N*DD bf16
  unsigned short* yb = xb + (size_t)NN * DD;                      // N*DD bf16
  int* epos = (int*)yb;  // E i32, aliases yb (dead before k_gather writes yb)
  unsigned short* WT2 = yb + (size_t)NN * DD;                     // 128*256 bf16

  hipMemsetAsync(base, 0, (size_t)NP * 8, stream); // degcnt

  k_deg<<<2048, 256, 0, stream>>>(col, ew, degcnt, epos, E);
  k_cast<<<2048, 256, 0, stream>>>(x, xb, NN * DD / 8);
  k_wt2<<<128, 64, 0, stream>>>(Wl, Wg, WT2);
  k_scan1<<<SCAN_BLKS, 256, 0, stream>>>(degcnt, bsum, N);
  k_scan2<<<1, 512, 0, stream>>>(bsum, SCAN_BLKS);
  k_scan3<<<SCAN_BLKS, 256, 0, stream>>>(degcnt, bsum, dis, rowptr, N);
  k_fill<<<2048, 256, 0, stream>>>(row, col, ew, dis, rowptr, epos, edgeA, E);
  k_gather<<<(N * 64 + 255) / 256, 256, 0, stream>>>(xb, rowptr, edgeA, yb, N);
  k_gemm<<<(N + 63) / 64, 256, 0, stream>>>(xb, yb, WT2, out, N);
}